// Round 1
// baseline (156.504 us; speedup 1.0000x reference)
//
#include <hip/hip_runtime.h>
#include <hip/hip_bf16.h>

#define BSZ 8192
#define BTZ 8192
#define DD 64
#define NC 10
#define LSE_SHIFT 48.0f

typedef __attribute__((ext_vector_type(8))) short bf16x8;
typedef __attribute__((ext_vector_type(4))) float f32x4;

__device__ __forceinline__ unsigned short f2bf_rne(float f) {
    unsigned int u = __float_as_uint(f);
    u += 0x7FFFu + ((u >> 16) & 1u);
    return (unsigned short)(u >> 16);
}

// Kernel A: f32 -> bf16 (RNE) for src/tgt features + src label histogram.
__global__ void kA(const float4* __restrict__ src4, const float4* __restrict__ tgt4,
                   const int* __restrict__ labels,
                   ushort4* __restrict__ srcb, ushort4* __restrict__ tgtb,
                   float* __restrict__ counts) {
    int tid = blockIdx.x * 256 + threadIdx.x;   // 131072 threads = 8192*64/4
    float4 s = src4[tid];
    ushort4 os; os.x = f2bf_rne(s.x); os.y = f2bf_rne(s.y);
    os.z = f2bf_rne(s.z); os.w = f2bf_rne(s.w);
    srcb[tid] = os;
    float4 t = tgt4[tid];
    ushort4 ot; ot.x = f2bf_rne(t.x); ot.y = f2bf_rne(t.y);
    ot.z = f2bf_rne(t.z); ot.w = f2bf_rne(t.w);
    tgtb[tid] = ot;
    if (tid < BSZ) atomicAdd(&counts[labels[tid]], 1.0f);
}

// Kernel B: per-tgt conf/cls -> colbias; confcount; class sums T (conf tgt) and SC (src).
__global__ void kB(const float* __restrict__ logits, const float* __restrict__ tgtf,
                   const float* __restrict__ srcf, const int* __restrict__ labels,
                   const float* __restrict__ counts,
                   float* __restrict__ colbias, float* __restrict__ confcount,
                   float* __restrict__ T, float* __restrict__ SC) {
    __shared__ int lcls[256];
    __shared__ float acc[4][NC * DD];
    __shared__ float hist[NC];
    int t = threadIdx.x;
    int i = blockIdx.x * 256 + t;

    float m1 = -3.0e38f, m2 = -3.0e38f; int cls = 0;
    #pragma unroll
    for (int c = 0; c < NC; ++c) {
        float v = logits[i * NC + c];
        if (v > m1) { m2 = m1; m1 = v; cls = c; }
        else if (v > m2) { m2 = v; }
    }
    bool conf = (m1 - m2) >= 0.1f;
    float cnt = counts[cls];
    colbias[i] = (conf && cnt > 0.0f) ? (logf(cnt) - LSE_SHIFT) : -1.0e30f;
    lcls[t] = conf ? cls : -1;
    if (t < NC) hist[t] = 0.0f;
    __syncthreads();
    if (conf) atomicAdd(&hist[cls], 1.0f);
    __syncthreads();
    if (t < NC) atomicAdd(&confcount[t], hist[t]);

    int rg = t >> 6, d = t & 63;
    // T: sums of confident tgt rows per class
    #pragma unroll
    for (int c = 0; c < NC; ++c) acc[rg][c * DD + d] = 0.0f;
    __syncthreads();
    for (int r = 0; r < 64; ++r) {
        int c = lcls[rg * 64 + r];
        if (c >= 0) acc[rg][c * DD + d] += tgtf[(blockIdx.x * 256 + rg * 64 + r) * DD + d];
    }
    __syncthreads();
    for (int o = t; o < NC * DD; o += 256)
        atomicAdd(&T[o], acc[0][o] + acc[1][o] + acc[2][o] + acc[3][o]);
    __syncthreads();
    // SC: sums of src rows per label
    lcls[t] = labels[i];
    #pragma unroll
    for (int c = 0; c < NC; ++c) acc[rg][c * DD + d] = 0.0f;
    __syncthreads();
    for (int r = 0; r < 64; ++r) {
        int c = lcls[rg * 64 + r];
        acc[rg][c * DD + d] += srcf[(blockIdx.x * 256 + rg * 64 + r) * DD + d];
    }
    __syncthreads();
    for (int o = t; o < NC * DD; o += 256)
        atomicAdd(&SC[o], acc[0][o] + acc[1][o] + acc[2][o] + acc[3][o]);
}

// Kernel C: fused bf16 MFMA GEMM + exp row-sum. Wave owns 64 src rows (4 m-blocks),
// sweeps 512 tgt columns in 16-wide tiles. A/B fragments loaded directly from
// global (16B/lane contiguous). S[j] accumulated via atomicAdd (16 adds/row).
__global__ __launch_bounds__(256) void kC(const unsigned short* __restrict__ srcb,
                                          const unsigned short* __restrict__ tgtb,
                                          const float* __restrict__ colbias,
                                          float* __restrict__ S) {
    int w = threadIdx.x >> 6;
    int lane = threadIdx.x & 63;
    int l15 = lane & 15;
    int quad = lane >> 4;
    int colchunk = blockIdx.x & 15;   // 16 column chunks of 512
    int rowg = blockIdx.x >> 4;       // 32 row groups of 256
    int row_base = rowg * 256 + w * 64;

    bf16x8 a[4][2];
    #pragma unroll
    for (int mb = 0; mb < 4; ++mb) {
        const bf16x8* p = (const bf16x8*)(srcb + (size_t)(row_base + mb * 16 + l15) * DD + quad * 8);
        a[mb][0] = p[0];   // k = quad*8 + j
        a[mb][1] = p[4];   // k = 32 + quad*8 + j
    }

    float rs[4][4];
    #pragma unroll
    for (int mb = 0; mb < 4; ++mb)
        #pragma unroll
        for (int r = 0; r < 4; ++r) rs[mb][r] = 0.0f;

    int col0 = colchunk * 512;
    for (int ct = 0; ct < 32; ++ct) {
        int cb = col0 + ct * 16;
        const bf16x8* q = (const bf16x8*)(tgtb + (size_t)(cb + l15) * DD + quad * 8);
        bf16x8 b0 = q[0];
        bf16x8 b1 = q[4];
        float cbias = colbias[cb + l15];   // C/D col = lane&15 for all 4 regs
        #pragma unroll
        for (int mb = 0; mb < 4; ++mb) {
            f32x4 acc = {0.0f, 0.0f, 0.0f, 0.0f};
            acc = __builtin_amdgcn_mfma_f32_16x16x32_bf16(a[mb][0], b0, acc, 0, 0, 0);
            acc = __builtin_amdgcn_mfma_f32_16x16x32_bf16(a[mb][1], b1, acc, 0, 0, 0);
            #pragma unroll
            for (int r = 0; r < 4; ++r)
                rs[mb][r] += __expf(acc[r] + cbias);
        }
    }

    // reduce the 16 column-lanes within each quad, then one atomic per row
    #pragma unroll
    for (int mb = 0; mb < 4; ++mb) {
        #pragma unroll
        for (int r = 0; r < 4; ++r) {
            float v = rs[mb][r];
            v += __shfl_xor(v, 1);
            v += __shfl_xor(v, 2);
            v += __shfl_xor(v, 4);
            v += __shfl_xor(v, 8);
            if (l15 == 0)
                atomicAdd(&S[row_base + mb * 16 + quad * 4 + r], v);
        }
    }
}

// Kernel D: single-block finale.
__global__ void kD(const float* __restrict__ S, const int* __restrict__ labels,
                   const float* __restrict__ counts, const float* __restrict__ confcount,
                   const float* __restrict__ T, const float* __restrict__ SC,
                   float* __restrict__ out) {
    int t = threadIdx.x;
    float termL = 0.0f, term1 = 0.0f, P = 0.0f;
    for (int j = t; j < BSZ; j += 256) {
        float L = logf(S[j]) + LSE_SHIFT;
        termL += confcount[labels[j]] * L;
    }
    for (int o = t; o < NC * DD; o += 256) term1 += SC[o] * T[o];
    for (int o = t; o < NC; o += 256) P += counts[o] * confcount[o];

    __shared__ float redL[4], red1[4], redP[4];
    int w = t >> 6, lane = t & 63;
    float v1 = termL, v2 = term1, v3 = P;
    #pragma unroll
    for (int m = 1; m < 64; m <<= 1) {
        v1 += __shfl_xor(v1, m);
        v2 += __shfl_xor(v2, m);
        v3 += __shfl_xor(v3, m);
    }
    if (lane == 0) { redL[w] = v1; red1[w] = v2; redP[w] = v3; }
    __syncthreads();
    if (t == 0) {
        float tl = redL[0] + redL[1] + redL[2] + redL[3];
        float t1 = red1[0] + red1[1] + red1[2] + red1[3];
        float p  = redP[0] + redP[1] + redP[2] + redP[3];
        out[0] = (t1 - tl) / (-(float)BSZ * p);
    }
}

extern "C" void kernel_launch(void* const* d_in, const int* in_sizes, int n_in,
                              void* d_out, int out_size, void* d_ws, size_t ws_size,
                              hipStream_t stream) {
    const float* src    = (const float*)d_in[0];
    const int*   labels = (const int*)d_in[1];
    const float* tgt    = (const float*)d_in[2];
    const float* logits = (const float*)d_in[3];

    char* ws = (char*)d_ws;
    float* S         = (float*)(ws + 0);           // 32768 B
    float* counts    = (float*)(ws + 32768);       // 64 B
    float* confcount = (float*)(ws + 32832);       // 64 B
    float* T         = (float*)(ws + 32896);       // 2560 B
    float* SC        = (float*)(ws + 35456);       // 2560 B
    float* colbias   = (float*)(ws + 40960);       // 32768 B (fully written by kB)
    unsigned short* srcb = (unsigned short*)(ws + 73728);            // 1 MiB
    unsigned short* tgtb = (unsigned short*)(ws + 73728 + 1048576);  // 1 MiB

    hipMemsetAsync(ws, 0, 40960, stream);  // zero S/counts/confcount/T/SC
    kA<<<512, 256, 0, stream>>>((const float4*)src, (const float4*)tgt, labels,
                                (ushort4*)srcb, (ushort4*)tgtb, counts);
    kB<<<32, 256, 0, stream>>>(logits, tgt, src, labels, counts,
                               colbias, confcount, T, SC);
    kC<<<512, 256, 0, stream>>>(srcb, tgtb, colbias, S);
    kD<<<1, 256, 0, stream>>>(S, labels, counts, confcount, T, SC, (float*)d_out);
}